// Round 8
// baseline (527.515 us; speedup 1.0000x reference)
//
#include <hip/hip_runtime.h>
#include <math.h>

#define N_NODES 50000
#define N_EDGES 800000
#define IN_F 768
#define HID 128
#define CLS 40
#define CLSP 48
#define CSTRIDE 64   // padded row stride (shorts) for hc
#define EPS 1e-5f
#define LNS2 132     // f32 LDS stride for gemm23 tile (mod4==0 for b128 packed reads)

typedef __attribute__((ext_vector_type(8))) short short8;
typedef __attribute__((ext_vector_type(4))) float f32x4;

__device__ inline unsigned short f2bf(float f) {
    union { float f; unsigned u; } x;
    x.f = f;
    unsigned u = x.u;
    return (unsigned short)((u + 0x7FFF + ((u >> 16) & 1)) >> 16);
}

__device__ inline float bf2f(unsigned short u) {
    union { unsigned u; float f; } x;
    x.u = ((unsigned)u) << 16;
    return x.f;
}

__device__ inline unsigned pack2bf(float a, float b) {
    return (unsigned)f2bf(a) | ((unsigned)f2bf(b) << 16);
}

// ---------------- degree ----------------

__global__ void k_deg(const int* __restrict__ src, const int* __restrict__ dst,
                      int* __restrict__ deg_out, int* __restrict__ deg_in) {
    int e = blockIdx.x * 256 + threadIdx.x;
    if (e < N_EDGES) {
        atomicAdd(&deg_out[src[e]], 1);
        atomicAdd(&deg_in[dst[e]], 1);
    }
}

// ---------------- unordered segment offsets (wave prefix + one atomic per wave) ----------------

__global__ void k_offsets(const int* __restrict__ deg_in, const int* __restrict__ deg_out,
                          int* __restrict__ start, float* __restrict__ do_is,
                          float* __restrict__ di_is, int* __restrict__ counter) {
    int i = blockIdx.x * 256 + threadIdx.x;
    int lane = threadIdx.x & 63;
    int d = (i < N_NODES) ? deg_in[i] : 0;
    int pre = d;
#pragma unroll
    for (int m = 1; m < 64; m <<= 1) {
        int v = __shfl_up(pre, m);
        if (lane >= m) pre += v;
    }
    int total = __shfl(pre, 63);
    int base = 0;
    if (lane == 63) base = atomicAdd(counter, total);
    base = __shfl(base, 63);
    if (i < N_NODES) {
        start[i] = base + pre - d;
        di_is[i] = rsqrtf((float)max(d, 1));
        do_is[i] = rsqrtf((float)max(deg_out[i], 1));
    }
}

__global__ void k_fill(const int* __restrict__ src, const int* __restrict__ dst,
                       const int* __restrict__ start, int* __restrict__ cnt,
                       int* __restrict__ col) {
    int e = blockIdx.x * 256 + threadIdx.x;
    if (e < N_EDGES) {
        int d = dst[e];
        int pos = start[d] + atomicAdd(&cnt[d], 1);
        col[pos] = src[e];
    }
}

// ---------------- all weight transposes+converts in one kernel ----------------

__global__ void k_cvtW_all(const float* __restrict__ W0, const float* __restrict__ W1,
                           const float* __restrict__ W2, unsigned short* __restrict__ Wt0,
                           unsigned short* __restrict__ Wt1, unsigned short* __restrict__ Wt2) {
    int idx = blockIdx.x * 256 + threadIdx.x;
    const int S0 = IN_F * HID;
    const int S1 = S0 + HID * HID;
    const int S2 = S1 + HID * CLSP;
    if (idx < S0) {
        int c = idx / IN_F, k = idx % IN_F;
        Wt0[idx] = f2bf(W0[(size_t)k * HID + c]);
    } else if (idx < S1) {
        int j = idx - S0;
        int c = j / HID, k = j % HID;
        Wt1[j] = f2bf(W1[(size_t)k * HID + c]);
    } else if (idx < S2) {
        int j = idx - S1;
        int c = j / HID, k = j % HID;
        Wt2[j] = (c < CLS) ? f2bf(W2[(size_t)k * CLS + c]) : (unsigned short)0;
    }
}

// ---------------- fused LN(768) + GEMM1, fully register-resident, no LDS ----------------
// h0 = bf16( (LN(feat)@W0) * do_is[row] ). Wave = 16 rows x 128 cols, independent.
// Lane l: row = l&15, k-quarter = l>>4. 4 quarter-lanes cover 128B/row contiguous.

__global__ void k_lngemm1r(const float* __restrict__ feat, const float* __restrict__ g,
                           const float* __restrict__ b, const unsigned short* __restrict__ Wt,
                           const float* __restrict__ do_is, unsigned short* __restrict__ out) {
    int t = threadIdx.x;
    int w = t >> 6, l = t & 63;
    int r0 = blockIdx.x * 64 + w * 16;
    int lrow = l & 15, lk8 = l >> 4;
    int row = r0 + lrow;
    if (row > N_NODES - 1) row = N_NODES - 1;
    const float4* x4 = (const float4*)(feat + (size_t)row * IN_F);
    const float4* g4 = (const float4*)g;
    const float4* b4 = (const float4*)b;

    // pass 1: load raw x in fragment layout; f32 stats; stash bf16 raw
    short8 a[24];
    float s = 0.f, q = 0.f;
#pragma unroll
    for (int j = 0; j < 24; j++) {
        float4 f0 = x4[j * 8 + lk8 * 2];
        float4 f1 = x4[j * 8 + lk8 * 2 + 1];
        s += f0.x + f0.y + f0.z + f0.w + f1.x + f1.y + f1.z + f1.w;
        q += f0.x * f0.x + f0.y * f0.y + f0.z * f0.z + f0.w * f0.w +
             f1.x * f1.x + f1.y * f1.y + f1.z * f1.z + f1.w * f1.w;
        short8 v;
        v[0] = (short)f2bf(f0.x); v[1] = (short)f2bf(f0.y);
        v[2] = (short)f2bf(f0.z); v[3] = (short)f2bf(f0.w);
        v[4] = (short)f2bf(f1.x); v[5] = (short)f2bf(f1.y);
        v[6] = (short)f2bf(f1.z); v[7] = (short)f2bf(f1.w);
        a[j] = v;
    }
    // reduce across the 4 lanes holding the same row (xor 16, 32)
    s += __shfl_xor(s, 16); q += __shfl_xor(q, 16);
    s += __shfl_xor(s, 32); q += __shfl_xor(q, 32);
    float mu = s * (1.f / (float)IN_F);
    float var = q * (1.f / (float)IN_F) - mu * mu;
    float rstd = rsqrtf(var + EPS);

    // pass 2: normalize in-register
#pragma unroll
    for (int j = 0; j < 24; j++) {
        float4 gg0 = g4[j * 8 + lk8 * 2];
        float4 gg1 = g4[j * 8 + lk8 * 2 + 1];
        float4 bb0 = b4[j * 8 + lk8 * 2];
        float4 bb1 = b4[j * 8 + lk8 * 2 + 1];
        short8 v = a[j];
        short8 y;
        y[0] = (short)f2bf((bf2f((unsigned short)v[0]) - mu) * rstd * gg0.x + bb0.x);
        y[1] = (short)f2bf((bf2f((unsigned short)v[1]) - mu) * rstd * gg0.y + bb0.y);
        y[2] = (short)f2bf((bf2f((unsigned short)v[2]) - mu) * rstd * gg0.z + bb0.z);
        y[3] = (short)f2bf((bf2f((unsigned short)v[3]) - mu) * rstd * gg0.w + bb0.w);
        y[4] = (short)f2bf((bf2f((unsigned short)v[4]) - mu) * rstd * gg1.x + bb1.x);
        y[5] = (short)f2bf((bf2f((unsigned short)v[5]) - mu) * rstd * gg1.y + bb1.y);
        y[6] = (short)f2bf((bf2f((unsigned short)v[6]) - mu) * rstd * gg1.z + bb1.z);
        y[7] = (short)f2bf((bf2f((unsigned short)v[7]) - mu) * rstd * gg1.w + bb1.w);
        a[j] = y;
    }

    // pass 3: K-loop, B streamed from L2
    f32x4 acc[8] = {};
#pragma unroll 2
    for (int j = 0; j < 24; j++) {
#pragma unroll
        for (int n = 0; n < 8; n++) {
            short8 bv = *(const short8*)(Wt + (size_t)(n * 16 + lrow) * IN_F + j * 32 + lk8 * 8);
            acc[n] = __builtin_amdgcn_mfma_f32_16x16x32_bf16(a[j], bv, acc[n], 0, 0, 0);
        }
    }

    // epilogue
#pragma unroll
    for (int n = 0; n < 8; n++) {
#pragma unroll
        for (int jj = 0; jj < 4; jj++) {
            int orow = r0 + lk8 * 4 + jj;
            if (orow < N_NODES) {
                float sc = do_is[orow];
                out[(size_t)orow * HID + n * 16 + lrow] = f2bf(acc[jj < 4 ? n : n][jj] * sc);
            }
        }
    }
}

// ---------------- GEMM2 + LN + ReLU + GEMM3 fused ----------------
// hc = bf16( relu(LN((hb@Wt1^T)*di))*do ) @ Wt2^T, written with padded CSTRIDE rows.

__global__ void k_gemm23(const unsigned short* __restrict__ A,
                         const unsigned short* __restrict__ Wt1,
                         const unsigned short* __restrict__ Wt2,
                         const float* __restrict__ di_is, const float* __restrict__ do_is,
                         const float* __restrict__ g, const float* __restrict__ b,
                         unsigned short* __restrict__ hc) {
    __shared__ float tile[64 * LNS2];  // 33.8 KB
    int t = threadIdx.x;
    int w = t >> 6, l = t & 63;
    int r0 = blockIdx.x * 64;
    int c0 = w * 32;
    int lrow = l & 15, lk8 = l >> 4;

    // --- GEMM2 ---
    const short8* ap[4];
#pragma unroll
    for (int m = 0; m < 4; m++) {
        int row = r0 + m * 16 + lrow;
        if (row > N_NODES - 1) row = N_NODES - 1;
        ap[m] = (const short8*)(A + (size_t)row * HID) + lk8;
    }
    const short8* bp[2];
#pragma unroll
    for (int n = 0; n < 2; n++) {
        bp[n] = (const short8*)(Wt1 + (size_t)(c0 + n * 16 + lrow) * HID) + lk8;
    }
    f32x4 acc[4][2] = {};
#pragma unroll
    for (int k0 = 0; k0 < HID / 8; k0 += 4) {
        short8 bv0 = bp[0][k0];
        short8 bv1 = bp[1][k0];
#pragma unroll
        for (int m = 0; m < 4; m++) {
            short8 av = ap[m][k0];
            acc[m][0] = __builtin_amdgcn_mfma_f32_16x16x32_bf16(av, bv0, acc[m][0], 0, 0, 0);
            acc[m][1] = __builtin_amdgcn_mfma_f32_16x16x32_bf16(av, bv1, acc[m][1], 0, 0, 0);
        }
    }
    // scaled pre-LN values -> f32 tile
#pragma unroll
    for (int m = 0; m < 4; m++) {
#pragma unroll
        for (int j = 0; j < 4; j++) {
            int rl = m * 16 + lk8 * 4 + j;
            int grow = r0 + rl;
            float sc = di_is[(grow < N_NODES) ? grow : (N_NODES - 1)];
            tile[rl * LNS2 + c0 + lrow] = acc[m][0][j] * sc;
            tile[rl * LNS2 + c0 + 16 + lrow] = acc[m][1][j] * sc;
        }
    }
    __syncthreads();

    // --- LN + ReLU + x do_is ---
    // RACE FIX (round 7 post-mortem): read ALL f32 inputs to registers, then
    // barrier, THEN overwrite the tile with packed bf16. Without the barrier,
    // lane qq=1's packed write of word 16+cc (iter cc) clobbers words that
    // lane qq=0 reads at iter 8+cc/2.
    int r = w * 16 + lrow;  // each wave LNs its own 16 rows
    int qq = lk8;           // quarter covers cols qq*32..+31
    float s1 = 0.f, s2 = 0.f;
#pragma unroll
    for (int c = 0; c < 32; c++) {
        int cs = (c + qq * 8) & 31;  // stagger to avoid q-lane bank collisions
        float v = tile[r * LNS2 + qq * 32 + cs];
        s1 += v;
        s2 += v * v;
    }
    s1 += __shfl_xor(s1, 16); s2 += __shfl_xor(s2, 16);
    s1 += __shfl_xor(s1, 32); s2 += __shfl_xor(s2, 32);
    float mu = s1 * (1.f / 128.f);
    float var = s2 * (1.f / 128.f) - mu * mu;
    float rstd = rsqrtf(var + EPS);
    int grow = r0 + r;
    float sc = do_is[(grow < N_NODES) ? grow : (N_NODES - 1)];

    float vv0[16], vv1[16];
#pragma unroll
    for (int cc = 0; cc < 16; cc++) {
        vv0[cc] = tile[r * LNS2 + qq * 32 + 2 * cc];
        vv1[cc] = tile[r * LNS2 + qq * 32 + 2 * cc + 1];
    }
    __syncthreads();  // all f32 reads complete before any packed overwrite

    unsigned* tu = (unsigned*)tile;
    const float2* g2 = (const float2*)(g + qq * 32);
    const float2* b2v = (const float2*)(b + qq * 32);
#pragma unroll
    for (int cc = 0; cc < 16; cc++) {
        float2 gg = g2[cc];
        float2 bb = b2v[cc];
        float y0 = fmaxf((vv0[cc] - mu) * rstd * gg.x + bb.x, 0.f) * sc;
        float y1 = fmaxf((vv1[cc] - mu) * rstd * gg.y + bb.y, 0.f) * sc;
        tu[r * LNS2 + qq * 16 + cc] = pack2bf(y0, y1);
    }
    __syncthreads();

    // --- GEMM3: wave w's 16 rows @ Wt2 (48 cols) ---
    const short8* bp2[3];
#pragma unroll
    for (int n = 0; n < 3; n++) {
        bp2[n] = (const short8*)(Wt2 + (size_t)(n * 16 + lrow) * HID) + lk8;
    }
    f32x4 a3[3] = {};
#pragma unroll
    for (int kf = 0; kf < 4; kf++) {
        short8 av = *(const short8*)(&tu[(w * 16 + lrow) * LNS2 + kf * 16 + lk8 * 4]);
#pragma unroll
        for (int n = 0; n < 3; n++) {
            a3[n] = __builtin_amdgcn_mfma_f32_16x16x32_bf16(av, bp2[n][kf * 4], a3[n], 0, 0, 0);
        }
    }
#pragma unroll
    for (int n = 0; n < 3; n++) {
        int colw = n * 16 + lrow;
#pragma unroll
        for (int j = 0; j < 4; j++) {
            int orow = r0 + w * 16 + lk8 * 4 + j;
            if (orow < N_NODES) hc[(size_t)orow * CSTRIDE + colw] = f2bf(a3[n][j]);
        }
    }
}

// ---------------- fused agg + LN + ReLU (layer 0), wave per node, 4x unrolled ----------------

__global__ void k_aggln(const unsigned short* __restrict__ h, const int* __restrict__ start,
                        const int* __restrict__ deg, const int* __restrict__ col,
                        const float* __restrict__ di_is, const float* __restrict__ do_is,
                        const float* __restrict__ g, const float* __restrict__ b,
                        unsigned* __restrict__ out) {
    int wid = (blockIdx.x * blockDim.x + threadIdx.x) >> 6;
    int lane = threadIdx.x & 63;
    if (wid >= N_NODES) return;
    int s0 = start[wid], e0 = s0 + deg[wid];
    const unsigned* h2 = (const unsigned*)h;
    float ax = 0.f, ay = 0.f;
    int i = s0;
    for (; i + 3 < e0; i += 4) {
        int c0_ = col[i], c1_ = col[i + 1], c2_ = col[i + 2], c3_ = col[i + 3];
        unsigned u0 = h2[(size_t)c0_ * 64 + lane];
        unsigned u1 = h2[(size_t)c1_ * 64 + lane];
        unsigned u2 = h2[(size_t)c2_ * 64 + lane];
        unsigned u3 = h2[(size_t)c3_ * 64 + lane];
        ax += bf2f((unsigned short)(u0 & 0xFFFF)) + bf2f((unsigned short)(u1 & 0xFFFF)) +
              bf2f((unsigned short)(u2 & 0xFFFF)) + bf2f((unsigned short)(u3 & 0xFFFF));
        ay += bf2f((unsigned short)(u0 >> 16)) + bf2f((unsigned short)(u1 >> 16)) +
              bf2f((unsigned short)(u2 >> 16)) + bf2f((unsigned short)(u3 >> 16));
    }
    for (; i < e0; i++) {
        unsigned u = h2[(size_t)col[i] * 64 + lane];
        ax += bf2f((unsigned short)(u & 0xFFFF));
        ay += bf2f((unsigned short)(u >> 16));
    }
    float di = di_is[wid];
    ax *= di; ay *= di;
    float s = ax + ay;
    float q = ax * ax + ay * ay;
#pragma unroll
    for (int m = 1; m < 64; m <<= 1) {
        s += __shfl_xor(s, m);
        q += __shfl_xor(q, m);
    }
    float mu = s * (1.f / 128.f);
    float var = q * (1.f / 128.f) - mu * mu;
    float rstd = rsqrtf(var + EPS);
    float2 gg = ((const float2*)g)[lane];
    float2 bb = ((const float2*)b)[lane];
    float sc = do_is[wid];
    float y0 = fmaxf((ax - mu) * rstd * gg.x + bb.x, 0.f) * sc;
    float y1 = fmaxf((ay - mu) * rstd * gg.y + bb.y, 0.f) * sc;
    out[(size_t)wid * 64 + lane] = pack2bf(y0, y1);
}

// ---------------- agg (layer 1), bf16 raw-sum out, wave per node, 4x unrolled ----------------

__global__ void k_agg128b(const unsigned short* __restrict__ h, const int* __restrict__ start,
                          const int* __restrict__ deg, const int* __restrict__ col,
                          unsigned* __restrict__ out) {
    int wid = (blockIdx.x * blockDim.x + threadIdx.x) >> 6;
    int lane = threadIdx.x & 63;
    if (wid >= N_NODES) return;
    int s0 = start[wid], e0 = s0 + deg[wid];
    const unsigned* h2 = (const unsigned*)h;
    float ax = 0.f, ay = 0.f;
    int i = s0;
    for (; i + 3 < e0; i += 4) {
        int c0_ = col[i], c1_ = col[i + 1], c2_ = col[i + 2], c3_ = col[i + 3];
        unsigned u0 = h2[(size_t)c0_ * 64 + lane];
        unsigned u1 = h2[(size_t)c1_ * 64 + lane];
        unsigned u2 = h2[(size_t)c2_ * 64 + lane];
        unsigned u3 = h2[(size_t)c3_ * 64 + lane];
        ax += bf2f((unsigned short)(u0 & 0xFFFF)) + bf2f((unsigned short)(u1 & 0xFFFF)) +
              bf2f((unsigned short)(u2 & 0xFFFF)) + bf2f((unsigned short)(u3 & 0xFFFF));
        ay += bf2f((unsigned short)(u0 >> 16)) + bf2f((unsigned short)(u1 >> 16)) +
              bf2f((unsigned short)(u2 >> 16)) + bf2f((unsigned short)(u3 >> 16));
    }
    for (; i < e0; i++) {
        unsigned u = h2[(size_t)col[i] * 64 + lane];
        ax += bf2f((unsigned short)(u & 0xFFFF));
        ay += bf2f((unsigned short)(u >> 16));
    }
    out[(size_t)wid * 64 + lane] = pack2bf(ax, ay);
}

// ---------------- agg (layer 2), padded 64-stride rows, wave per node ----------------

__global__ void k_agg40b(const unsigned short* __restrict__ h, const int* __restrict__ start,
                         const int* __restrict__ deg, const int* __restrict__ col,
                         const float* __restrict__ di_is, const float* __restrict__ b2,
                         float* __restrict__ out) {
    int wid = (blockIdx.x * blockDim.x + threadIdx.x) >> 6;
    int lane = threadIdx.x & 63;
    if (wid >= N_NODES) return;
    int s0 = start[wid], e0 = s0 + deg[wid];
    float acc = 0.f;
    int i = s0;
    for (; i + 3 < e0; i += 4) {
        int c0_ = col[i], c1_ = col[i + 1], c2_ = col[i + 2], c3_ = col[i + 3];
        float v0 = bf2f(h[(size_t)c0_ * CSTRIDE + lane]);
        float v1 = bf2f(h[(size_t)c1_ * CSTRIDE + lane]);
        float v2 = bf2f(h[(size_t)c2_ * CSTRIDE + lane]);
        float v3 = bf2f(h[(size_t)c3_ * CSTRIDE + lane]);
        acc += v0 + v1 + v2 + v3;
    }
    for (; i < e0; i++) acc += bf2f(h[(size_t)col[i] * CSTRIDE + lane]);
    if (lane < CLS) out[(size_t)wid * CLS + lane] = acc * di_is[wid] + b2[lane];
}

// ---------------- launch ----------------

extern "C" void kernel_launch(void* const* d_in, const int* in_sizes, int n_in,
                              void* d_out, int out_size, void* d_ws, size_t ws_size,
                              hipStream_t stream) {
    (void)in_sizes; (void)n_in; (void)out_size; (void)ws_size;
    const float* feat = (const float*)d_in[0];
    const int*   src  = (const int*)d_in[1];
    const int*   dst  = (const int*)d_in[2];
    const float* W0   = (const float*)d_in[3];
    const float* W1   = (const float*)d_in[4];
    const float* W2   = (const float*)d_in[5];
    const float* b2   = (const float*)d_in[6];
    const float* g_in = (const float*)d_in[7];
    const float* b_in = (const float*)d_in[8];
    const float* g0   = (const float*)d_in[9];
    const float* b0   = (const float*)d_in[10];
    const float* g1   = (const float*)d_in[11];
    const float* b1   = (const float*)d_in[12];
    float* out = (float*)d_out;

    char* w = (char*)d_ws;
    size_t off = 0;
    auto take = [&](size_t bytes) -> void* {
        void* p = w + off;
        off += (bytes + 255) & ~(size_t)255;
        return p;
    };
    const size_t SZN = ((size_t)N_NODES * 4 + 255) & ~(size_t)255;
    char* zblk      = (char*)take(3 * SZN + 256);
    int*  deg_out_i = (int*)zblk;
    int*  deg_in_i  = (int*)(zblk + SZN);
    int*  cnt       = (int*)(zblk + 2 * SZN);
    int*  counter   = (int*)(zblk + 3 * SZN);

    float* do_is     = (float*)take((size_t)N_NODES * 4);
    float* di_is     = (float*)take((size_t)N_NODES * 4);
    int*   start     = (int*)take((size_t)N_NODES * 4);
    int*   col       = (int*)take((size_t)N_EDGES * 4);
    unsigned short* Wt0 = (unsigned short*)take((size_t)IN_F * HID * 2);
    unsigned short* Wt1 = (unsigned short*)take((size_t)HID * HID * 2);
    unsigned short* Wt2 = (unsigned short*)take((size_t)HID * CLSP * 2);
    unsigned short* h0  = (unsigned short*)take((size_t)N_NODES * HID * 2);
    unsigned short* h1  = (unsigned short*)take((size_t)N_NODES * HID * 2);
    unsigned short* hb  = (unsigned short*)take((size_t)N_NODES * HID * 2);
    unsigned short* hc  = (unsigned short*)take((size_t)N_NODES * CSTRIDE * 2);

    const int NB_E = (N_EDGES + 255) / 256;
    const int NB_N = (N_NODES + 255) / 256;
    const int NB_M64 = (N_NODES + 63) / 64;
    const int NB_WAVE = (N_NODES * 64 + 255) / 256;
    const int CVTN = IN_F * HID + HID * HID + HID * CLSP;

    hipMemsetAsync(zblk, 0, 3 * SZN + 256, stream);

    k_deg<<<NB_E, 256, 0, stream>>>(src, dst, deg_out_i, deg_in_i);
    k_offsets<<<NB_N, 256, 0, stream>>>(deg_in_i, deg_out_i, start, do_is, di_is, counter);
    k_fill<<<NB_E, 256, 0, stream>>>(src, dst, start, cnt, col);

    k_cvtW_all<<<(CVTN + 255) / 256, 256, 0, stream>>>(W0, W1, W2, Wt0, Wt1, Wt2);

    // Layer 0: h0 = (LN(feat)@W0)*do_is ; h1 = relu(LN(agg(h0)*di_is))*do_is
    k_lngemm1r<<<NB_M64, 256, 0, stream>>>(feat, g_in, b_in, Wt0, do_is, h0);
    k_aggln<<<NB_WAVE, 256, 0, stream>>>(h0, start, deg_in_i, col, di_is, do_is, g0, b0, (unsigned*)h1);

    // Layer 1+2a: hb = agg(h1) ; hc = (relu(LN((hb@W1)*di_is))*do_is) @ W2
    k_agg128b<<<NB_WAVE, 256, 0, stream>>>(h1, start, deg_in_i, col, (unsigned*)hb);
    k_gemm23<<<NB_M64, 256, 0, stream>>>(hb, Wt1, Wt2, di_is, do_is, g1, b1, hc);

    // Layer 2b: out = agg(hc)*di_is + b2
    k_agg40b<<<NB_WAVE, 256, 0, stream>>>(hc, start, deg_in_i, col, di_is, b2, out);
}

// Round 9
// 345.901 us; speedup vs baseline: 1.5250x; 1.5250x over previous
//
#include <hip/hip_runtime.h>
#include <math.h>

#define N_NODES 50000
#define N_EDGES 800000
#define IN_F 768
#define HID 128
#define CLS 40
#define CLSP 48
#define CSTRIDE 64   // padded row stride (shorts) for hc
#define EPS 1e-5f
#define LNS2 132     // f32 LDS stride for gemm23 tile
#define AS_STR 776   // bf16 LDS stride (shorts) for lngemm1 A tile (2-way bank aliasing, free)

typedef __attribute__((ext_vector_type(8))) short short8;
typedef __attribute__((ext_vector_type(4))) float f32x4;

__device__ inline unsigned short f2bf(float f) {
    union { float f; unsigned u; } x;
    x.f = f;
    unsigned u = x.u;
    return (unsigned short)((u + 0x7FFF + ((u >> 16) & 1)) >> 16);
}

__device__ inline float bf2f(unsigned short u) {
    union { unsigned u; float f; } x;
    x.u = ((unsigned)u) << 16;
    return x.f;
}

__device__ inline unsigned pack2bf(float a, float b) {
    return (unsigned)f2bf(a) | ((unsigned)f2bf(b) << 16);
}

// ---------------- degree ----------------

__global__ void k_deg(const int* __restrict__ src, const int* __restrict__ dst,
                      int* __restrict__ deg_out, int* __restrict__ deg_in) {
    int e = blockIdx.x * 256 + threadIdx.x;
    if (e < N_EDGES) {
        atomicAdd(&deg_out[src[e]], 1);
        atomicAdd(&deg_in[dst[e]], 1);
    }
}

// ---------------- unordered segment offsets ----------------

__global__ void k_offsets(const int* __restrict__ deg_in, const int* __restrict__ deg_out,
                          int* __restrict__ start, float* __restrict__ do_is,
                          float* __restrict__ di_is, int* __restrict__ counter) {
    int i = blockIdx.x * 256 + threadIdx.x;
    int lane = threadIdx.x & 63;
    int d = (i < N_NODES) ? deg_in[i] : 0;
    int pre = d;
#pragma unroll
    for (int m = 1; m < 64; m <<= 1) {
        int v = __shfl_up(pre, m);
        if (lane >= m) pre += v;
    }
    int total = __shfl(pre, 63);
    int base = 0;
    if (lane == 63) base = atomicAdd(counter, total);
    base = __shfl(base, 63);
    if (i < N_NODES) {
        start[i] = base + pre - d;
        di_is[i] = rsqrtf((float)max(d, 1));
        do_is[i] = rsqrtf((float)max(deg_out[i], 1));
    }
}

__global__ void k_fill(const int* __restrict__ src, const int* __restrict__ dst,
                       const int* __restrict__ start, int* __restrict__ cnt,
                       int* __restrict__ col) {
    int e = blockIdx.x * 256 + threadIdx.x;
    if (e < N_EDGES) {
        int d = dst[e];
        int pos = start[d] + atomicAdd(&cnt[d], 1);
        col[pos] = src[e];
    }
}

// ---------------- all weight transposes+converts ----------------

__global__ void k_cvtW_all(const float* __restrict__ W0, const float* __restrict__ W1,
                           const float* __restrict__ W2, unsigned short* __restrict__ Wt0,
                           unsigned short* __restrict__ Wt1, unsigned short* __restrict__ Wt2) {
    int idx = blockIdx.x * 256 + threadIdx.x;
    const int S0 = IN_F * HID;
    const int S1 = S0 + HID * HID;
    const int S2 = S1 + HID * CLSP;
    if (idx < S0) {
        int c = idx / IN_F, k = idx % IN_F;
        Wt0[idx] = f2bf(W0[(size_t)k * HID + c]);
    } else if (idx < S1) {
        int j = idx - S0;
        int c = j / HID, k = j % HID;
        Wt1[j] = f2bf(W1[(size_t)k * HID + c]);
    } else if (idx < S2) {
        int j = idx - S1;
        int c = j / HID, k = j % HID;
        Wt2[j] = (c < CLS) ? f2bf(W2[(size_t)k * CLS + c]) : (unsigned short)0;
    }
}

// ---------------- fused LN(768) + GEMM1 (MFMA), 16-row blocks, 24.3 KB LDS ----------------
// h0 = bf16( (LN(feat)@W0) * do_is[row] ). Block: 256 thr (4 waves), 16 rows.
// Phase 1: wave w LNs rows w*4..w*4+3 (coalesced float4), bf16 -> LDS.
// Phase 2: wave w computes 16 rows x cols [w*32, w*32+32): 1 m-frag, 2 n-frags.

__global__ void k_lngemm1(const float* __restrict__ feat, const float* __restrict__ g,
                          const float* __restrict__ b, const unsigned short* __restrict__ Wt,
                          const float* __restrict__ do_is, unsigned short* __restrict__ out) {
    __shared__ unsigned short As[16 * AS_STR];  // 24832 B -> 6 blocks/CU
    int t = threadIdx.x;
    int w = t >> 6, l = t & 63;
    int r0 = blockIdx.x * 16;

    // ---- phase 1: LN rows w*4 .. w*4+3 ----
    const float4* g4 = (const float4*)g;
    const float4* b4 = (const float4*)b;
#pragma unroll
    for (int rr = 0; rr < 4; rr++) {
        int lr = w * 4 + rr;
        int grow = r0 + lr;
        if (grow > N_NODES - 1) grow = N_NODES - 1;
        const float4* x4 = (const float4*)(feat + (size_t)grow * IN_F);
        float4 v[3];
        float s = 0.f, q = 0.f;
#pragma unroll
        for (int i = 0; i < 3; i++) {
            float4 tv = x4[l + 64 * i];
            v[i] = tv;
            s += tv.x + tv.y + tv.z + tv.w;
            q += tv.x * tv.x + tv.y * tv.y + tv.z * tv.z + tv.w * tv.w;
        }
#pragma unroll
        for (int m = 1; m < 64; m <<= 1) {
            s += __shfl_xor(s, m);
            q += __shfl_xor(q, m);
        }
        float mu = s * (1.f / (float)IN_F);
        float var = q * (1.f / (float)IN_F) - mu * mu;
        float rstd = rsqrtf(var + EPS);
        ushort4* arow = (ushort4*)(&As[lr * AS_STR]);
#pragma unroll
        for (int i = 0; i < 3; i++) {
            int f = l + 64 * i;
            float4 gg = g4[f];
            float4 bb = b4[f];
            ushort4 o;
            o.x = f2bf((v[i].x - mu) * rstd * gg.x + bb.x);
            o.y = f2bf((v[i].y - mu) * rstd * gg.y + bb.y);
            o.z = f2bf((v[i].z - mu) * rstd * gg.z + bb.z);
            o.w = f2bf((v[i].w - mu) * rstd * gg.w + bb.w);
            arow[f] = o;
        }
    }
    __syncthreads();

    // ---- phase 2: MFMA, 16 rows x 32 cols per wave ----
    int c0 = w * 32;
    int lrow = l & 15;
    int lk8 = l >> 4;

    const short8* bp[2];
#pragma unroll
    for (int n = 0; n < 2; n++) {
        bp[n] = (const short8*)(Wt + (size_t)(c0 + n * 16 + lrow) * IN_F) + lk8;
    }

    f32x4 acc[2] = {};
#pragma unroll 4
    for (int j = 0; j < 24; j++) {
        short8 av = *(const short8*)(&As[lrow * AS_STR + j * 32 + lk8 * 8]);
        acc[0] = __builtin_amdgcn_mfma_f32_16x16x32_bf16(av, bp[0][j * 4], acc[0], 0, 0, 0);
        acc[1] = __builtin_amdgcn_mfma_f32_16x16x32_bf16(av, bp[1][j * 4], acc[1], 0, 0, 0);
    }

#pragma unroll
    for (int jj = 0; jj < 4; jj++) {
        int orow = r0 + lk8 * 4 + jj;
        if (orow < N_NODES) {
            float sc = do_is[orow];
            out[(size_t)orow * HID + c0 + lrow] = f2bf(acc[0][jj] * sc);
            out[(size_t)orow * HID + c0 + 16 + lrow] = f2bf(acc[1][jj] * sc);
        }
    }
}

// ---------------- GEMM2 + LN + ReLU + GEMM3 fused ----------------

__global__ void k_gemm23(const unsigned short* __restrict__ A,
                         const unsigned short* __restrict__ Wt1,
                         const unsigned short* __restrict__ Wt2,
                         const float* __restrict__ di_is, const float* __restrict__ do_is,
                         const float* __restrict__ g, const float* __restrict__ b,
                         unsigned short* __restrict__ hc) {
    __shared__ float tile[64 * LNS2];  // 33.8 KB
    int t = threadIdx.x;
    int w = t >> 6, l = t & 63;
    int r0 = blockIdx.x * 64;
    int c0 = w * 32;
    int lrow = l & 15, lk8 = l >> 4;

    // --- GEMM2 ---
    const short8* ap[4];
#pragma unroll
    for (int m = 0; m < 4; m++) {
        int row = r0 + m * 16 + lrow;
        if (row > N_NODES - 1) row = N_NODES - 1;
        ap[m] = (const short8*)(A + (size_t)row * HID) + lk8;
    }
    const short8* bp[2];
#pragma unroll
    for (int n = 0; n < 2; n++) {
        bp[n] = (const short8*)(Wt1 + (size_t)(c0 + n * 16 + lrow) * HID) + lk8;
    }
    f32x4 acc[4][2] = {};
#pragma unroll
    for (int k0 = 0; k0 < HID / 8; k0 += 4) {
        short8 bv0 = bp[0][k0];
        short8 bv1 = bp[1][k0];
#pragma unroll
        for (int m = 0; m < 4; m++) {
            short8 av = ap[m][k0];
            acc[m][0] = __builtin_amdgcn_mfma_f32_16x16x32_bf16(av, bv0, acc[m][0], 0, 0, 0);
            acc[m][1] = __builtin_amdgcn_mfma_f32_16x16x32_bf16(av, bv1, acc[m][1], 0, 0, 0);
        }
    }
#pragma unroll
    for (int m = 0; m < 4; m++) {
#pragma unroll
        for (int j = 0; j < 4; j++) {
            int rl = m * 16 + lk8 * 4 + j;
            int grow = r0 + rl;
            float sc = di_is[(grow < N_NODES) ? grow : (N_NODES - 1)];
            tile[rl * LNS2 + c0 + lrow] = acc[m][0][j] * sc;
            tile[rl * LNS2 + c0 + 16 + lrow] = acc[m][1][j] * sc;
        }
    }
    __syncthreads();

    // --- LN + ReLU + x do_is (read-all -> barrier -> packed overwrite; round-7 race fix) ---
    int r = w * 16 + lrow;
    int qq = lk8;
    float s1 = 0.f, s2 = 0.f;
#pragma unroll
    for (int c = 0; c < 32; c++) {
        int cs = (c + qq * 8) & 31;
        float v = tile[r * LNS2 + qq * 32 + cs];
        s1 += v;
        s2 += v * v;
    }
    s1 += __shfl_xor(s1, 16); s2 += __shfl_xor(s2, 16);
    s1 += __shfl_xor(s1, 32); s2 += __shfl_xor(s2, 32);
    float mu = s1 * (1.f / 128.f);
    float var = s2 * (1.f / 128.f) - mu * mu;
    float rstd = rsqrtf(var + EPS);
    int grow = r0 + r;
    float sc = do_is[(grow < N_NODES) ? grow : (N_NODES - 1)];

    float vv0[16], vv1[16];
#pragma unroll
    for (int cc = 0; cc < 16; cc++) {
        vv0[cc] = tile[r * LNS2 + qq * 32 + 2 * cc];
        vv1[cc] = tile[r * LNS2 + qq * 32 + 2 * cc + 1];
    }
    __syncthreads();

    unsigned* tu = (unsigned*)tile;
    const float2* g2 = (const float2*)(g + qq * 32);
    const float2* b2v = (const float2*)(b + qq * 32);
#pragma unroll
    for (int cc = 0; cc < 16; cc++) {
        float2 gg = g2[cc];
        float2 bb = b2v[cc];
        float y0 = fmaxf((vv0[cc] - mu) * rstd * gg.x + bb.x, 0.f) * sc;
        float y1 = fmaxf((vv1[cc] - mu) * rstd * gg.y + bb.y, 0.f) * sc;
        tu[r * LNS2 + qq * 16 + cc] = pack2bf(y0, y1);
    }
    __syncthreads();

    // --- GEMM3 ---
    const short8* bp2[3];
#pragma unroll
    for (int n = 0; n < 3; n++) {
        bp2[n] = (const short8*)(Wt2 + (size_t)(n * 16 + lrow) * HID) + lk8;
    }
    f32x4 a3[3] = {};
#pragma unroll
    for (int kf = 0; kf < 4; kf++) {
        short8 av = *(const short8*)(&tu[(w * 16 + lrow) * LNS2 + kf * 16 + lk8 * 4]);
#pragma unroll
        for (int n = 0; n < 3; n++) {
            a3[n] = __builtin_amdgcn_mfma_f32_16x16x32_bf16(av, bp2[n][kf * 4], a3[n], 0, 0, 0);
        }
    }
#pragma unroll
    for (int n = 0; n < 3; n++) {
        int colw = n * 16 + lrow;
#pragma unroll
        for (int j = 0; j < 4; j++) {
            int orow = r0 + w * 16 + lk8 * 4 + j;
            if (orow < N_NODES) hc[(size_t)orow * CSTRIDE + colw] = f2bf(a3[n][j]);
        }
    }
}

// ---------------- fused agg + LN + ReLU (layer 0), wave per node, 8x unrolled ----------------

__global__ void k_aggln(const unsigned short* __restrict__ h, const int* __restrict__ start,
                        const int* __restrict__ deg, const int* __restrict__ col,
                        const float* __restrict__ di_is, const float* __restrict__ do_is,
                        const float* __restrict__ g, const float* __restrict__ b,
                        unsigned* __restrict__ out) {
    int wid = (blockIdx.x * blockDim.x + threadIdx.x) >> 6;
    int lane = threadIdx.x & 63;
    if (wid >= N_NODES) return;
    int s0 = start[wid], e0 = s0 + deg[wid];
    const unsigned* h2 = (const unsigned*)h;
    float ax = 0.f, ay = 0.f;
    int i = s0;
    for (; i + 7 < e0; i += 8) {
        unsigned u[8];
#pragma unroll
        for (int k = 0; k < 8; k++) u[k] = h2[(size_t)col[i + k] * 64 + lane];
#pragma unroll
        for (int k = 0; k < 8; k++) {
            ax += bf2f((unsigned short)(u[k] & 0xFFFF));
            ay += bf2f((unsigned short)(u[k] >> 16));
        }
    }
    for (; i < e0; i++) {
        unsigned u = h2[(size_t)col[i] * 64 + lane];
        ax += bf2f((unsigned short)(u & 0xFFFF));
        ay += bf2f((unsigned short)(u >> 16));
    }
    float di = di_is[wid];
    ax *= di; ay *= di;
    float s = ax + ay;
    float q = ax * ax + ay * ay;
#pragma unroll
    for (int m = 1; m < 64; m <<= 1) {
        s += __shfl_xor(s, m);
        q += __shfl_xor(q, m);
    }
    float mu = s * (1.f / 128.f);
    float var = q * (1.f / 128.f) - mu * mu;
    float rstd = rsqrtf(var + EPS);
    float2 gg = ((const float2*)g)[lane];
    float2 bb = ((const float2*)b)[lane];
    float sc = do_is[wid];
    float y0 = fmaxf((ax - mu) * rstd * gg.x + bb.x, 0.f) * sc;
    float y1 = fmaxf((ay - mu) * rstd * gg.y + bb.y, 0.f) * sc;
    out[(size_t)wid * 64 + lane] = pack2bf(y0, y1);
}

// ---------------- agg (layer 1), bf16 raw-sum out, wave per node, 8x unrolled ----------------

__global__ void k_agg128b(const unsigned short* __restrict__ h, const int* __restrict__ start,
                          const int* __restrict__ deg, const int* __restrict__ col,
                          unsigned* __restrict__ out) {
    int wid = (blockIdx.x * blockDim.x + threadIdx.x) >> 6;
    int lane = threadIdx.x & 63;
    if (wid >= N_NODES) return;
    int s0 = start[wid], e0 = s0 + deg[wid];
    const unsigned* h2 = (const unsigned*)h;
    float ax = 0.f, ay = 0.f;
    int i = s0;
    for (; i + 7 < e0; i += 8) {
        unsigned u[8];
#pragma unroll
        for (int k = 0; k < 8; k++) u[k] = h2[(size_t)col[i + k] * 64 + lane];
#pragma unroll
        for (int k = 0; k < 8; k++) {
            ax += bf2f((unsigned short)(u[k] & 0xFFFF));
            ay += bf2f((unsigned short)(u[k] >> 16));
        }
    }
    for (; i < e0; i++) {
        unsigned u = h2[(size_t)col[i] * 64 + lane];
        ax += bf2f((unsigned short)(u & 0xFFFF));
        ay += bf2f((unsigned short)(u >> 16));
    }
    out[(size_t)wid * 64 + lane] = pack2bf(ax, ay);
}

// ---------------- agg (layer 2), padded 64-stride rows, wave per node, 8x unrolled ----------------

__global__ void k_agg40b(const unsigned short* __restrict__ h, const int* __restrict__ start,
                         const int* __restrict__ deg, const int* __restrict__ col,
                         const float* __restrict__ di_is, const float* __restrict__ b2,
                         float* __restrict__ out) {
    int wid = (blockIdx.x * blockDim.x + threadIdx.x) >> 6;
    int lane = threadIdx.x & 63;
    if (wid >= N_NODES) return;
    int s0 = start[wid], e0 = s0 + deg[wid];
    float acc = 0.f;
    int i = s0;
    for (; i + 7 < e0; i += 8) {
        float v[8];
#pragma unroll
        for (int k = 0; k < 8; k++) v[k] = bf2f(h[(size_t)col[i + k] * CSTRIDE + lane]);
#pragma unroll
        for (int k = 0; k < 8; k++) acc += v[k];
    }
    for (; i < e0; i++) acc += bf2f(h[(size_t)col[i] * CSTRIDE + lane]);
    if (lane < CLS) out[(size_t)wid * CLS + lane] = acc * di_is[wid] + b2[lane];
}

// ---------------- launch ----------------

extern "C" void kernel_launch(void* const* d_in, const int* in_sizes, int n_in,
                              void* d_out, int out_size, void* d_ws, size_t ws_size,
                              hipStream_t stream) {
    (void)in_sizes; (void)n_in; (void)out_size; (void)ws_size;
    const float* feat = (const float*)d_in[0];
    const int*   src  = (const int*)d_in[1];
    const int*   dst  = (const int*)d_in[2];
    const float* W0   = (const float*)d_in[3];
    const float* W1   = (const float*)d_in[4];
    const float* W2   = (const float*)d_in[5];
    const float* b2   = (const float*)d_in[6];
    const float* g_in = (const float*)d_in[7];
    const float* b_in = (const float*)d_in[8];
    const float* g0   = (const float*)d_in[9];
    const float* b0   = (const float*)d_in[10];
    const float* g1   = (const float*)d_in[11];
    const float* b1   = (const float*)d_in[12];
    float* out = (float*)d_out;

    char* w = (char*)d_ws;
    size_t off = 0;
    auto take = [&](size_t bytes) -> void* {
        void* p = w + off;
        off += (bytes + 255) & ~(size_t)255;
        return p;
    };
    const size_t SZN = ((size_t)N_NODES * 4 + 255) & ~(size_t)255;
    char* zblk      = (char*)take(3 * SZN + 256);
    int*  deg_out_i = (int*)zblk;
    int*  deg_in_i  = (int*)(zblk + SZN);
    int*  cnt       = (int*)(zblk + 2 * SZN);
    int*  counter   = (int*)(zblk + 3 * SZN);

    float* do_is     = (float*)take((size_t)N_NODES * 4);
    float* di_is     = (float*)take((size_t)N_NODES * 4);
    int*   start     = (int*)take((size_t)N_NODES * 4);
    int*   col       = (int*)take((size_t)N_EDGES * 4);
    unsigned short* Wt0 = (unsigned short*)take((size_t)IN_F * HID * 2);
    unsigned short* Wt1 = (unsigned short*)take((size_t)HID * HID * 2);
    unsigned short* Wt2 = (unsigned short*)take((size_t)HID * CLSP * 2);
    unsigned short* h0  = (unsigned short*)take((size_t)N_NODES * HID * 2);
    unsigned short* h1  = (unsigned short*)take((size_t)N_NODES * HID * 2);
    unsigned short* hb  = (unsigned short*)take((size_t)N_NODES * HID * 2);
    unsigned short* hc  = (unsigned short*)take((size_t)N_NODES * CSTRIDE * 2);

    const int NB_E = (N_EDGES + 255) / 256;
    const int NB_N = (N_NODES + 255) / 256;
    const int NB_M16 = (N_NODES + 15) / 16;
    const int NB_M64 = (N_NODES + 63) / 64;
    const int NB_WAVE = (N_NODES * 64 + 255) / 256;
    const int CVTN = IN_F * HID + HID * HID + HID * CLSP;

    hipMemsetAsync(zblk, 0, 3 * SZN + 256, stream);

    k_deg<<<NB_E, 256, 0, stream>>>(src, dst, deg_out_i, deg_in_i);
    k_offsets<<<NB_N, 256, 0, stream>>>(deg_in_i, deg_out_i, start, do_is, di_is, counter);
    k_fill<<<NB_E, 256, 0, stream>>>(src, dst, start, cnt, col);

    k_cvtW_all<<<(CVTN + 255) / 256, 256, 0, stream>>>(W0, W1, W2, Wt0, Wt1, Wt2);

    // Layer 0: h0 = (LN(feat)@W0)*do_is ; h1 = relu(LN(agg(h0)*di_is))*do_is
    k_lngemm1<<<NB_M16, 256, 0, stream>>>(feat, g_in, b_in, Wt0, do_is, h0);
    k_aggln<<<NB_WAVE, 256, 0, stream>>>(h0, start, deg_in_i, col, di_is, do_is, g0, b0, (unsigned*)h1);

    // Layer 1+2a: hb = agg(h1) ; hc = (relu(LN((hb@W1)*di_is))*do_is) @ W2
    k_agg128b<<<NB_WAVE, 256, 0, stream>>>(h1, start, deg_in_i, col, (unsigned*)hb);
    k_gemm23<<<NB_M64, 256, 0, stream>>>(hb, Wt1, Wt2, di_is, do_is, g1, b1, hc);

    // Layer 2b: out = agg(hc)*di_is + b2
    k_agg40b<<<NB_WAVE, 256, 0, stream>>>(hc, start, deg_in_i, col, di_is, b2, out);
}

// Round 10
// 323.116 us; speedup vs baseline: 1.6326x; 1.0705x over previous
//
#include <hip/hip_runtime.h>
#include <math.h>

#define N_NODES 50000
#define N_EDGES 800000
#define IN_F 768
#define HID 128
#define CLS 40
#define CLSP 48
#define CSTRIDE 64   // padded row stride (shorts) for hc
#define EPS 1e-5f
#define LNS2 132     // f32 LDS stride for gemm23 tile
#define AS_STR 776   // bf16 LDS stride (shorts): 1552B row, 388 words, 388%32=4 -> 2-way aliasing (free)

typedef __attribute__((ext_vector_type(8))) short short8;
typedef __attribute__((ext_vector_type(4))) float f32x4;

__device__ inline unsigned short f2bf(float f) {
    union { float f; unsigned u; } x;
    x.f = f;
    unsigned u = x.u;
    return (unsigned short)((u + 0x7FFF + ((u >> 16) & 1)) >> 16);
}

__device__ inline float bf2f(unsigned short u) {
    union { unsigned u; float f; } x;
    x.u = ((unsigned)u) << 16;
    return x.f;
}

__device__ inline unsigned pack2bf(float a, float b) {
    return (unsigned)f2bf(a) | ((unsigned)f2bf(b) << 16);
}

// ---------------- degree ----------------

__global__ void k_deg(const int* __restrict__ src, const int* __restrict__ dst,
                      int* __restrict__ deg_out, int* __restrict__ deg_in) {
    int e = blockIdx.x * 256 + threadIdx.x;
    if (e < N_EDGES) {
        atomicAdd(&deg_out[src[e]], 1);
        atomicAdd(&deg_in[dst[e]], 1);
    }
}

// ---------------- unordered segment offsets ----------------

__global__ void k_offsets(const int* __restrict__ deg_in, const int* __restrict__ deg_out,
                          int* __restrict__ start, float* __restrict__ do_is,
                          float* __restrict__ di_is, int* __restrict__ counter) {
    int i = blockIdx.x * 256 + threadIdx.x;
    int lane = threadIdx.x & 63;
    int d = (i < N_NODES) ? deg_in[i] : 0;
    int pre = d;
#pragma unroll
    for (int m = 1; m < 64; m <<= 1) {
        int v = __shfl_up(pre, m);
        if (lane >= m) pre += v;
    }
    int total = __shfl(pre, 63);
    int base = 0;
    if (lane == 63) base = atomicAdd(counter, total);
    base = __shfl(base, 63);
    if (i < N_NODES) {
        start[i] = base + pre - d;
        di_is[i] = rsqrtf((float)max(d, 1));
        do_is[i] = rsqrtf((float)max(deg_out[i], 1));
    }
}

__global__ void k_fill(const int* __restrict__ src, const int* __restrict__ dst,
                       const int* __restrict__ start, int* __restrict__ cnt,
                       int* __restrict__ col) {
    int e = blockIdx.x * 256 + threadIdx.x;
    if (e < N_EDGES) {
        int d = dst[e];
        int pos = start[d] + atomicAdd(&cnt[d], 1);
        col[pos] = src[e];
    }
}

// ---------------- all weight transposes+converts ----------------

__global__ void k_cvtW_all(const float* __restrict__ W0, const float* __restrict__ W1,
                           const float* __restrict__ W2, unsigned short* __restrict__ Wt0,
                           unsigned short* __restrict__ Wt1, unsigned short* __restrict__ Wt2) {
    int idx = blockIdx.x * 256 + threadIdx.x;
    const int S0 = IN_F * HID;
    const int S1 = S0 + HID * HID;
    const int S2 = S1 + HID * CLSP;
    if (idx < S0) {
        int c = idx / IN_F, k = idx % IN_F;
        Wt0[idx] = f2bf(W0[(size_t)k * HID + c]);
    } else if (idx < S1) {
        int j = idx - S0;
        int c = j / HID, k = j % HID;
        Wt1[j] = f2bf(W1[(size_t)k * HID + c]);
    } else if (idx < S2) {
        int j = idx - S1;
        int c = j / HID, k = j % HID;
        Wt2[j] = (c < CLS) ? f2bf(W2[(size_t)k * CLS + c]) : (unsigned short)0;
    }
}

// ---------------- fused LN(768) + GEMM1 (MFMA), 32-row blocks, upfront loads ----------------
// h0 = bf16( (LN(feat)@W0) * do_is[row] ). Block: 256 thr (4 waves), 32 rows.
// Phase 1: wave w owns rows w*8..w*8+7; ALL 24 float4 loads issued before any
// reduction (ILP fix for round-9's serial chain); g/b loaded once, reused x8.
// Phase 2: wave w computes 32 rows x cols [w*32,+32): 2 m-frags x 2 n-frags,
// B fragment reused across both m-frags (B traffic amortized over 32 rows).

__global__ __launch_bounds__(256, 3) void k_lngemm1(
        const float* __restrict__ feat, const float* __restrict__ g,
        const float* __restrict__ b, const unsigned short* __restrict__ Wt,
        const float* __restrict__ do_is, unsigned short* __restrict__ out) {
    __shared__ unsigned short As[32 * AS_STR];  // 48.5 KB -> 3 blocks/CU
    int t = threadIdx.x;
    int w = t >> 6, l = t & 63;
    int r0 = blockIdx.x * 32;

    // ---- phase 1 ----
    const float4* g4 = (const float4*)g;
    const float4* b4 = (const float4*)b;
    float4 gv[3], bv_[3];
#pragma unroll
    for (int i = 0; i < 3; i++) { gv[i] = g4[l + 64 * i]; bv_[i] = b4[l + 64 * i]; }

    float4 v[8][3];
#pragma unroll
    for (int rr = 0; rr < 8; rr++) {
        int grow = r0 + w * 8 + rr;
        if (grow > N_NODES - 1) grow = N_NODES - 1;
        const float4* x4 = (const float4*)(feat + (size_t)grow * IN_F);
#pragma unroll
        for (int i = 0; i < 3; i++) v[rr][i] = x4[l + 64 * i];
    }

    float s[8], q[8];
#pragma unroll
    for (int rr = 0; rr < 8; rr++) {
        float ss = 0.f, qq = 0.f;
#pragma unroll
        for (int i = 0; i < 3; i++) {
            float4 tv = v[rr][i];
            ss += tv.x + tv.y + tv.z + tv.w;
            qq += tv.x * tv.x + tv.y * tv.y + tv.z * tv.z + tv.w * tv.w;
        }
        s[rr] = ss; q[rr] = qq;
    }
    // 8 independent shuffle chains -> interleaved by scheduler
#pragma unroll
    for (int m = 1; m < 64; m <<= 1) {
#pragma unroll
        for (int rr = 0; rr < 8; rr++) {
            s[rr] += __shfl_xor(s[rr], m);
            q[rr] += __shfl_xor(q[rr], m);
        }
    }
#pragma unroll
    for (int rr = 0; rr < 8; rr++) {
        int lr = w * 8 + rr;
        float mu = s[rr] * (1.f / (float)IN_F);
        float var = q[rr] * (1.f / (float)IN_F) - mu * mu;
        float rstd = rsqrtf(var + EPS);
        ushort4* arow = (ushort4*)(&As[lr * AS_STR]);
#pragma unroll
        for (int i = 0; i < 3; i++) {
            float4 tv = v[rr][i];
            ushort4 o;
            o.x = f2bf((tv.x - mu) * rstd * gv[i].x + bv_[i].x);
            o.y = f2bf((tv.y - mu) * rstd * gv[i].y + bv_[i].y);
            o.z = f2bf((tv.z - mu) * rstd * gv[i].z + bv_[i].z);
            o.w = f2bf((tv.w - mu) * rstd * gv[i].w + bv_[i].w);
            arow[l + 64 * i] = o;
        }
    }
    __syncthreads();

    // ---- phase 2: 32 rows x 32 cols per wave ----
    int c0 = w * 32;
    int lrow = l & 15;
    int lk8 = l >> 4;

    const short8* bp0 = (const short8*)(Wt + (size_t)(c0 + lrow) * IN_F) + lk8;
    const short8* bp1 = (const short8*)(Wt + (size_t)(c0 + 16 + lrow) * IN_F) + lk8;

    f32x4 acc[2][2] = {};
#pragma unroll 4
    for (int j = 0; j < 24; j++) {
        short8 b0 = bp0[j * 4];
        short8 b1 = bp1[j * 4];
        short8 a0 = *(const short8*)(&As[lrow * AS_STR + j * 32 + lk8 * 8]);
        short8 a1 = *(const short8*)(&As[(16 + lrow) * AS_STR + j * 32 + lk8 * 8]);
        acc[0][0] = __builtin_amdgcn_mfma_f32_16x16x32_bf16(a0, b0, acc[0][0], 0, 0, 0);
        acc[0][1] = __builtin_amdgcn_mfma_f32_16x16x32_bf16(a0, b1, acc[0][1], 0, 0, 0);
        acc[1][0] = __builtin_amdgcn_mfma_f32_16x16x32_bf16(a1, b0, acc[1][0], 0, 0, 0);
        acc[1][1] = __builtin_amdgcn_mfma_f32_16x16x32_bf16(a1, b1, acc[1][1], 0, 0, 0);
    }

#pragma unroll
    for (int m = 0; m < 2; m++) {
#pragma unroll
        for (int jj = 0; jj < 4; jj++) {
            int orow = r0 + m * 16 + lk8 * 4 + jj;
            if (orow < N_NODES) {
                float sc = do_is[orow];
                out[(size_t)orow * HID + c0 + lrow] = f2bf(acc[m][0][jj] * sc);
                out[(size_t)orow * HID + c0 + 16 + lrow] = f2bf(acc[m][1][jj] * sc);
            }
        }
    }
}

// ---------------- GEMM2 + LN + ReLU + GEMM3 fused ----------------

__global__ void k_gemm23(const unsigned short* __restrict__ A,
                         const unsigned short* __restrict__ Wt1,
                         const unsigned short* __restrict__ Wt2,
                         const float* __restrict__ di_is, const float* __restrict__ do_is,
                         const float* __restrict__ g, const float* __restrict__ b,
                         unsigned short* __restrict__ hc) {
    __shared__ float tile[64 * LNS2];  // 33.8 KB
    int t = threadIdx.x;
    int w = t >> 6, l = t & 63;
    int r0 = blockIdx.x * 64;
    int c0 = w * 32;
    int lrow = l & 15, lk8 = l >> 4;

    // --- GEMM2 ---
    const short8* ap[4];
#pragma unroll
    for (int m = 0; m < 4; m++) {
        int row = r0 + m * 16 + lrow;
        if (row > N_NODES - 1) row = N_NODES - 1;
        ap[m] = (const short8*)(A + (size_t)row * HID) + lk8;
    }
    const short8* bp[2];
#pragma unroll
    for (int n = 0; n < 2; n++) {
        bp[n] = (const short8*)(Wt1 + (size_t)(c0 + n * 16 + lrow) * HID) + lk8;
    }
    f32x4 acc[4][2] = {};
#pragma unroll
    for (int k0 = 0; k0 < HID / 8; k0 += 4) {
        short8 bv0 = bp[0][k0];
        short8 bv1 = bp[1][k0];
#pragma unroll
        for (int m = 0; m < 4; m++) {
            short8 av = ap[m][k0];
            acc[m][0] = __builtin_amdgcn_mfma_f32_16x16x32_bf16(av, bv0, acc[m][0], 0, 0, 0);
            acc[m][1] = __builtin_amdgcn_mfma_f32_16x16x32_bf16(av, bv1, acc[m][1], 0, 0, 0);
        }
    }
#pragma unroll
    for (int m = 0; m < 4; m++) {
#pragma unroll
        for (int j = 0; j < 4; j++) {
            int rl = m * 16 + lk8 * 4 + j;
            int grow = r0 + rl;
            float sc = di_is[(grow < N_NODES) ? grow : (N_NODES - 1)];
            tile[rl * LNS2 + c0 + lrow] = acc[m][0][j] * sc;
            tile[rl * LNS2 + c0 + 16 + lrow] = acc[m][1][j] * sc;
        }
    }
    __syncthreads();

    // --- LN + ReLU + x do_is (read-all -> barrier -> packed overwrite; round-7 race fix) ---
    int r = w * 16 + lrow;
    int qq = lk8;
    float s1 = 0.f, s2 = 0.f;
#pragma unroll
    for (int c = 0; c < 32; c++) {
        int cs = (c + qq * 8) & 31;
        float v = tile[r * LNS2 + qq * 32 + cs];
        s1 += v;
        s2 += v * v;
    }
    s1 += __shfl_xor(s1, 16); s2 += __shfl_xor(s2, 16);
    s1 += __shfl_xor(s1, 32); s2 += __shfl_xor(s2, 32);
    float mu = s1 * (1.f / 128.f);
    float var = s2 * (1.f / 128.f) - mu * mu;
    float rstd = rsqrtf(var + EPS);
    int grow = r0 + r;
    float sc = do_is[(grow < N_NODES) ? grow : (N_NODES - 1)];

    float vv0[16], vv1[16];
#pragma unroll
    for (int cc = 0; cc < 16; cc++) {
        vv0[cc] = tile[r * LNS2 + qq * 32 + 2 * cc];
        vv1[cc] = tile[r * LNS2 + qq * 32 + 2 * cc + 1];
    }
    __syncthreads();

    unsigned* tu = (unsigned*)tile;
    const float2* g2 = (const float2*)(g + qq * 32);
    const float2* b2v = (const float2*)(b + qq * 32);
#pragma unroll
    for (int cc = 0; cc < 16; cc++) {
        float2 gg = g2[cc];
        float2 bb = b2v[cc];
        float y0 = fmaxf((vv0[cc] - mu) * rstd * gg.x + bb.x, 0.f) * sc;
        float y1 = fmaxf((vv1[cc] - mu) * rstd * gg.y + bb.y, 0.f) * sc;
        tu[r * LNS2 + qq * 16 + cc] = pack2bf(y0, y1);
    }
    __syncthreads();

    // --- GEMM3 ---
    const short8* bp2[3];
#pragma unroll
    for (int n = 0; n < 3; n++) {
        bp2[n] = (const short8*)(Wt2 + (size_t)(n * 16 + lrow) * HID) + lk8;
    }
    f32x4 a3[3] = {};
#pragma unroll
    for (int kf = 0; kf < 4; kf++) {
        short8 av = *(const short8*)(&tu[(w * 16 + lrow) * LNS2 + kf * 16 + lk8 * 4]);
#pragma unroll
        for (int n = 0; n < 3; n++) {
            a3[n] = __builtin_amdgcn_mfma_f32_16x16x32_bf16(av, bp2[n][kf * 4], a3[n], 0, 0, 0);
        }
    }
#pragma unroll
    for (int n = 0; n < 3; n++) {
        int colw = n * 16 + lrow;
#pragma unroll
        for (int j = 0; j < 4; j++) {
            int orow = r0 + w * 16 + lk8 * 4 + j;
            if (orow < N_NODES) hc[(size_t)orow * CSTRIDE + colw] = f2bf(a3[n][j]);
        }
    }
}

// ---------------- fused agg + LN + ReLU (layer 0), wave per node, 8x unrolled ----------------

__global__ void k_aggln(const unsigned short* __restrict__ h, const int* __restrict__ start,
                        const int* __restrict__ deg, const int* __restrict__ col,
                        const float* __restrict__ di_is, const float* __restrict__ do_is,
                        const float* __restrict__ g, const float* __restrict__ b,
                        unsigned* __restrict__ out) {
    int wid = (blockIdx.x * blockDim.x + threadIdx.x) >> 6;
    int lane = threadIdx.x & 63;
    if (wid >= N_NODES) return;
    int s0 = start[wid], e0 = s0 + deg[wid];
    const unsigned* h2 = (const unsigned*)h;
    float ax = 0.f, ay = 0.f;
    int i = s0;
    for (; i + 7 < e0; i += 8) {
        unsigned u[8];
#pragma unroll
        for (int k = 0; k < 8; k++) u[k] = h2[(size_t)col[i + k] * 64 + lane];
#pragma unroll
        for (int k = 0; k < 8; k++) {
            ax += bf2f((unsigned short)(u[k] & 0xFFFF));
            ay += bf2f((unsigned short)(u[k] >> 16));
        }
    }
    for (; i < e0; i++) {
        unsigned u = h2[(size_t)col[i] * 64 + lane];
        ax += bf2f((unsigned short)(u & 0xFFFF));
        ay += bf2f((unsigned short)(u >> 16));
    }
    float di = di_is[wid];
    ax *= di; ay *= di;
    float s = ax + ay;
    float q = ax * ax + ay * ay;
#pragma unroll
    for (int m = 1; m < 64; m <<= 1) {
        s += __shfl_xor(s, m);
        q += __shfl_xor(q, m);
    }
    float mu = s * (1.f / 128.f);
    float var = q * (1.f / 128.f) - mu * mu;
    float rstd = rsqrtf(var + EPS);
    float2 gg = ((const float2*)g)[lane];
    float2 bb = ((const float2*)b)[lane];
    float sc = do_is[wid];
    float y0 = fmaxf((ax - mu) * rstd * gg.x + bb.x, 0.f) * sc;
    float y1 = fmaxf((ay - mu) * rstd * gg.y + bb.y, 0.f) * sc;
    out[(size_t)wid * 64 + lane] = pack2bf(y0, y1);
}

// ---------------- agg (layer 1), bf16 raw-sum out, wave per node, 8x unrolled ----------------

__global__ void k_agg128b(const unsigned short* __restrict__ h, const int* __restrict__ start,
                          const int* __restrict__ deg, const int* __restrict__ col,
                          unsigned* __restrict__ out) {
    int wid = (blockIdx.x * blockDim.x + threadIdx.x) >> 6;
    int lane = threadIdx.x & 63;
    if (wid >= N_NODES) return;
    int s0 = start[wid], e0 = s0 + deg[wid];
    const unsigned* h2 = (const unsigned*)h;
    float ax = 0.f, ay = 0.f;
    int i = s0;
    for (; i + 7 < e0; i += 8) {
        unsigned u[8];
#pragma unroll
        for (int k = 0; k < 8; k++) u[k] = h2[(size_t)col[i + k] * 64 + lane];
#pragma unroll
        for (int k = 0; k < 8; k++) {
            ax += bf2f((unsigned short)(u[k] & 0xFFFF));
            ay += bf2f((unsigned short)(u[k] >> 16));
        }
    }
    for (; i < e0; i++) {
        unsigned u = h2[(size_t)col[i] * 64 + lane];
        ax += bf2f((unsigned short)(u & 0xFFFF));
        ay += bf2f((unsigned short)(u >> 16));
    }
    out[(size_t)wid * 64 + lane] = pack2bf(ax, ay);
}

// ---------------- agg (layer 2), padded 64-stride rows, wave per node, 8x unrolled ----------------

__global__ void k_agg40b(const unsigned short* __restrict__ h, const int* __restrict__ start,
                         const int* __restrict__ deg, const int* __restrict__ col,
                         const float* __restrict__ di_is, const float* __restrict__ b2,
                         float* __restrict__ out) {
    int wid = (blockIdx.x * blockDim.x + threadIdx.x) >> 6;
    int lane = threadIdx.x & 63;
    if (wid >= N_NODES) return;
    int s0 = start[wid], e0 = s0 + deg[wid];
    float acc = 0.f;
    int i = s0;
    for (; i + 7 < e0; i += 8) {
        float v[8];
#pragma unroll
        for (int k = 0; k < 8; k++) v[k] = bf2f(h[(size_t)col[i + k] * CSTRIDE + lane]);
#pragma unroll
        for (int k = 0; k < 8; k++) acc += v[k];
    }
    for (; i < e0; i++) acc += bf2f(h[(size_t)col[i] * CSTRIDE + lane]);
    if (lane < CLS) out[(size_t)wid * CLS + lane] = acc * di_is[wid] + b2[lane];
}

// ---------------- launch ----------------

extern "C" void kernel_launch(void* const* d_in, const int* in_sizes, int n_in,
                              void* d_out, int out_size, void* d_ws, size_t ws_size,
                              hipStream_t stream) {
    (void)in_sizes; (void)n_in; (void)out_size; (void)ws_size;
    const float* feat = (const float*)d_in[0];
    const int*   src  = (const int*)d_in[1];
    const int*   dst  = (const int*)d_in[2];
    const float* W0   = (const float*)d_in[3];
    const float* W1   = (const float*)d_in[4];
    const float* W2   = (const float*)d_in[5];
    const float* b2   = (const float*)d_in[6];
    const float* g_in = (const float*)d_in[7];
    const float* b_in = (const float*)d_in[8];
    const float* g0   = (const float*)d_in[9];
    const float* b0   = (const float*)d_in[10];
    const float* g1   = (const float*)d_in[11];
    const float* b1   = (const float*)d_in[12];
    float* out = (float*)d_out;

    char* w = (char*)d_ws;
    size_t off = 0;
    auto take = [&](size_t bytes) -> void* {
        void* p = w + off;
        off += (bytes + 255) & ~(size_t)255;
        return p;
    };
    const size_t SZN = ((size_t)N_NODES * 4 + 255) & ~(size_t)255;
    char* zblk      = (char*)take(3 * SZN + 256);
    int*  deg_out_i = (int*)zblk;
    int*  deg_in_i  = (int*)(zblk + SZN);
    int*  cnt       = (int*)(zblk + 2 * SZN);
    int*  counter   = (int*)(zblk + 3 * SZN);

    float* do_is     = (float*)take((size_t)N_NODES * 4);
    float* di_is     = (float*)take((size_t)N_NODES * 4);
    int*   start     = (int*)take((size_t)N_NODES * 4);
    int*   col       = (int*)take((size_t)N_EDGES * 4);
    unsigned short* Wt0 = (unsigned short*)take((size_t)IN_F * HID * 2);
    unsigned short* Wt1 = (unsigned short*)take((size_t)HID * HID * 2);
    unsigned short* Wt2 = (unsigned short*)take((size_t)HID * CLSP * 2);
    unsigned short* h0  = (unsigned short*)take((size_t)N_NODES * HID * 2);
    unsigned short* h1  = (unsigned short*)take((size_t)N_NODES * HID * 2);
    unsigned short* hb  = (unsigned short*)take((size_t)N_NODES * HID * 2);
    unsigned short* hc  = (unsigned short*)take((size_t)N_NODES * CSTRIDE * 2);

    const int NB_E = (N_EDGES + 255) / 256;
    const int NB_N = (N_NODES + 255) / 256;
    const int NB_M32 = (N_NODES + 31) / 32;
    const int NB_M64 = (N_NODES + 63) / 64;
    const int NB_WAVE = (N_NODES * 64 + 255) / 256;
    const int CVTN = IN_F * HID + HID * HID + HID * CLSP;

    hipMemsetAsync(zblk, 0, 3 * SZN + 256, stream);

    k_deg<<<NB_E, 256, 0, stream>>>(src, dst, deg_out_i, deg_in_i);
    k_offsets<<<NB_N, 256, 0, stream>>>(deg_in_i, deg_out_i, start, do_is, di_is, counter);
    k_fill<<<NB_E, 256, 0, stream>>>(src, dst, start, cnt, col);

    k_cvtW_all<<<(CVTN + 255) / 256, 256, 0, stream>>>(W0, W1, W2, Wt0, Wt1, Wt2);

    // Layer 0: h0 = (LN(feat)@W0)*do_is ; h1 = relu(LN(agg(h0)*di_is))*do_is
    k_lngemm1<<<NB_M32, 256, 0, stream>>>(feat, g_in, b_in, Wt0, do_is, h0);
    k_aggln<<<NB_WAVE, 256, 0, stream>>>(h0, start, deg_in_i, col, di_is, do_is, g0, b0, (unsigned*)h1);

    // Layer 1+2a: hb = agg(h1) ; hc = (relu(LN((hb@W1)*di_is))*do_is) @ W2
    k_agg128b<<<NB_WAVE, 256, 0, stream>>>(h1, start, deg_in_i, col, (unsigned*)hb);
    k_gemm23<<<NB_M64, 256, 0, stream>>>(hb, Wt1, Wt2, di_is, do_is, g1, b1, hc);

    // Layer 2b: out = agg(hc)*di_is + b2
    k_agg40b<<<NB_WAVE, 256, 0, stream>>>(hc, start, deg_in_i, col, di_is, b2, out);
}